// Round 9
// baseline (57.600 us; speedup 1.0000x reference)
//
#include <hip/hip_runtime.h>

// FractalEmbedding: tokens -> Julia features (16 fp32) -> 16x2048 projection.
// Output 268 MB fp32 => store-bound. Fill ceiling 7 TB/s => ~38 us floor.
//
// R9: R8 minus the in-block serial prologue. Feats precomputed by a separate
// tiny kernel into d_ws; proj kernel is a pure stream: no LDS, no barrier,
// no gathers. Feats read via wave-uniform f32x4 loads (L2-resident).
// Keeps: contiguous 512 KB/block, 8 dims/thread (2 chunks: 1 KB wave bursts),
// pk_fma with scale folded, 2-token ILP unroll, plain f32x4 stores.

constexpr int TOKENS = 4 * 8192;   // 32768
constexpr int EMBED  = 2048;
constexpr int NF     = 16;         // 2 * STEPS
constexpr int STEPS  = 8;
constexpr int TB     = 64;         // tokens per block

typedef float f32x2 __attribute__((ext_vector_type(2)));
typedef float f32x4 __attribute__((ext_vector_type(4)));

// ---------------- kernel 1: Julia features ----------------
__global__ __launch_bounds__(64)
void feats_kernel(const int* __restrict__ tok,
                  const float* __restrict__ crt,
                  const float* __restrict__ cit,
                  float* __restrict__ feats)   // [TOKENS][NF]
{
    const int t = blockIdx.x * 64 + threadIdx.x;
    const int id = tok[t];
    const float cr = crt[id];
    const float ci = cit[id];
    float f[NF];
    float zr = 0.0f, zi = 0.0f;
    #pragma unroll
    for (int st = 0; st < STEPS; ++st) {
        const float nzr = zr * zr - zi * zi + cr;
        const float nzi = 2.0f * zr * zi + ci;
        zr = nzr; zi = nzi;
        f[2 * st]     = zr;
        f[2 * st + 1] = zi;
    }
    f32x4* fo = reinterpret_cast<f32x4*>(feats + (size_t)t * NF);
    #pragma unroll
    for (int j = 0; j < 4; ++j) {
        f32x4 v = { f[4 * j], f[4 * j + 1], f[4 * j + 2], f[4 * j + 3] };
        fo[j] = v;
    }
}

// ---------------- kernel 2: projection, pure stream ----------------
__global__ __launch_bounds__(256, 2)
void proj_kernel(const float* __restrict__ feats,  // [TOKENS][NF] in d_ws
                 const float* __restrict__ W,      // [EMBED][NF]
                 const float* __restrict__ scale_p,
                 float* __restrict__ out)          // [TOKENS][EMBED]
{
    const int tid = threadIdx.x;
    const int dlo = tid * 4;           // chunk 0: dims dlo..dlo+3
    const int dhi = 1024 + tid * 4;    // chunk 1: dims dhi..dhi+3
    const float s = scale_p[0];

    // Packed weights, scale folded: wp[c][p][k] = {W[d+2p][k], W[d+2p+1][k]}*s
    f32x2 wp[2][2][NF];
    #pragma unroll
    for (int c = 0; c < 2; ++c) {
        const int d = (c == 0) ? dlo : dhi;
        const f32x4* W4 = reinterpret_cast<const f32x4*>(W + (size_t)d * NF);
        #pragma unroll
        for (int p = 0; p < 2; ++p) {
            #pragma unroll
            for (int k = 0; k < 4; ++k) {
                f32x4 a = W4[p * 8 + k];       // row d+2p
                f32x4 b = W4[p * 8 + 4 + k];   // row d+2p+1
                wp[c][p][4 * k + 0] = (f32x2){ a.x * s, b.x * s };
                wp[c][p][4 * k + 1] = (f32x2){ a.y * s, b.y * s };
                wp[c][p][4 * k + 2] = (f32x2){ a.z * s, b.z * s };
                wp[c][p][4 * k + 3] = (f32x2){ a.w * s, b.w * s };
            }
        }
    }

    const int tok0 = blockIdx.x * TB;
    const float* fbase = feats + (size_t)tok0 * NF;
    float* __restrict__ olo = out + (size_t)tok0 * EMBED + dlo;
    float* __restrict__ ohi = out + (size_t)tok0 * EMBED + dhi;

    for (int i = 0; i < TB; i += 2) {
        // Wave-uniform feats loads (L2-resident, scalar-load candidates).
        float fa[NF], fb[NF];
        {
            const f32x4* fpa = reinterpret_cast<const f32x4*>(fbase + i * NF);
            const f32x4* fpb = reinterpret_cast<const f32x4*>(fbase + (i + 1) * NF);
            #pragma unroll
            for (int k = 0; k < 4; ++k) {
                f32x4 va = fpa[k], vb = fpb[k];
                fa[4 * k + 0] = va.x; fa[4 * k + 1] = va.y;
                fa[4 * k + 2] = va.z; fa[4 * k + 3] = va.w;
                fb[4 * k + 0] = vb.x; fb[4 * k + 1] = vb.y;
                fb[4 * k + 2] = vb.z; fb[4 * k + 3] = vb.w;
            }
        }
        f32x2 aL0 = {0.f,0.f}, aL1 = {0.f,0.f}, aH0 = {0.f,0.f}, aH1 = {0.f,0.f};
        f32x2 bL0 = {0.f,0.f}, bL1 = {0.f,0.f}, bH0 = {0.f,0.f}, bH1 = {0.f,0.f};
        #pragma unroll
        for (int k = 0; k < NF; ++k) {
            const f32x2 fA = { fa[k], fa[k] };
            const f32x2 fB = { fb[k], fb[k] };
            aL0 += fA * wp[0][0][k];   // v_pk_fma_f32
            aL1 += fA * wp[0][1][k];
            aH0 += fA * wp[1][0][k];
            aH1 += fA * wp[1][1][k];
            bL0 += fB * wp[0][0][k];
            bL1 += fB * wp[0][1][k];
            bH0 += fB * wp[1][0][k];
            bH1 += fB * wp[1][1][k];
        }
        const size_t r0 = (size_t)i * EMBED;
        const size_t r1 = (size_t)(i + 1) * EMBED;
        *reinterpret_cast<f32x4*>(olo + r0) = (f32x4){ aL0.x, aL0.y, aL1.x, aL1.y };
        *reinterpret_cast<f32x4*>(ohi + r0) = (f32x4){ aH0.x, aH0.y, aH1.x, aH1.y };
        *reinterpret_cast<f32x4*>(olo + r1) = (f32x4){ bL0.x, bL0.y, bL1.x, bL1.y };
        *reinterpret_cast<f32x4*>(ohi + r1) = (f32x4){ bH0.x, bH0.y, bH1.x, bH1.y };
    }
}

// ---------------- fallback (fused R8) if ws too small ----------------
__global__ __launch_bounds__(256, 2)
void fused_kernel(const int* __restrict__ tok,
                  const float* __restrict__ crt,
                  const float* __restrict__ cit,
                  const float* __restrict__ W,
                  const float* __restrict__ scale_p,
                  float* __restrict__ out)
{
    const int tid = threadIdx.x;
    const int dlo = tid * 4;
    const int dhi = 1024 + tid * 4;
    const float s = scale_p[0];
    f32x2 wp[2][2][NF];
    #pragma unroll
    for (int c = 0; c < 2; ++c) {
        const int d = (c == 0) ? dlo : dhi;
        const f32x4* W4 = reinterpret_cast<const f32x4*>(W + (size_t)d * NF);
        #pragma unroll
        for (int p = 0; p < 2; ++p) {
            #pragma unroll
            for (int k = 0; k < 4; ++k) {
                f32x4 a = W4[p * 8 + k];
                f32x4 b = W4[p * 8 + 4 + k];
                wp[c][p][4 * k + 0] = (f32x2){ a.x * s, b.x * s };
                wp[c][p][4 * k + 1] = (f32x2){ a.y * s, b.y * s };
                wp[c][p][4 * k + 2] = (f32x2){ a.z * s, b.z * s };
                wp[c][p][4 * k + 3] = (f32x2){ a.w * s, b.w * s };
            }
        }
    }
    __shared__ float feats[TB][NF];
    const int tok0 = blockIdx.x * TB;
    if (tid < TB) {
        const int t = tok[tok0 + tid];
        const float cr = crt[t], ci = cit[t];
        float zr = 0.0f, zi = 0.0f;
        #pragma unroll
        for (int st = 0; st < STEPS; ++st) {
            const float nzr = zr * zr - zi * zi + cr;
            const float nzi = 2.0f * zr * zi + ci;
            zr = nzr; zi = nzi;
            feats[tid][2 * st] = zr; feats[tid][2 * st + 1] = zi;
        }
    }
    __syncthreads();
    float* __restrict__ olo = out + (size_t)tok0 * EMBED + dlo;
    float* __restrict__ ohi = out + (size_t)tok0 * EMBED + dhi;
    for (int i = 0; i < TB; i += 2) {
        float fa[NF], fb[NF];
        {
            const f32x4* fpa = reinterpret_cast<const f32x4*>(feats[i]);
            const f32x4* fpb = reinterpret_cast<const f32x4*>(feats[i + 1]);
            #pragma unroll
            for (int k = 0; k < 4; ++k) {
                f32x4 va = fpa[k], vb = fpb[k];
                fa[4 * k + 0] = va.x; fa[4 * k + 1] = va.y;
                fa[4 * k + 2] = va.z; fa[4 * k + 3] = va.w;
                fb[4 * k + 0] = vb.x; fb[4 * k + 1] = vb.y;
                fb[4 * k + 2] = vb.z; fb[4 * k + 3] = vb.w;
            }
        }
        f32x2 aL0 = {0.f,0.f}, aL1 = {0.f,0.f}, aH0 = {0.f,0.f}, aH1 = {0.f,0.f};
        f32x2 bL0 = {0.f,0.f}, bL1 = {0.f,0.f}, bH0 = {0.f,0.f}, bH1 = {0.f,0.f};
        #pragma unroll
        for (int k = 0; k < NF; ++k) {
            const f32x2 fA = { fa[k], fa[k] };
            const f32x2 fB = { fb[k], fb[k] };
            aL0 += fA * wp[0][0][k];
            aL1 += fA * wp[0][1][k];
            aH0 += fA * wp[1][0][k];
            aH1 += fA * wp[1][1][k];
            bL0 += fB * wp[0][0][k];
            bL1 += fB * wp[0][1][k];
            bH0 += fB * wp[1][0][k];
            bH1 += fB * wp[1][1][k];
        }
        const size_t r0 = (size_t)i * EMBED;
        const size_t r1 = (size_t)(i + 1) * EMBED;
        *reinterpret_cast<f32x4*>(olo + r0) = (f32x4){ aL0.x, aL0.y, aL1.x, aL1.y };
        *reinterpret_cast<f32x4*>(ohi + r0) = (f32x4){ aH0.x, aH0.y, aH1.x, aH1.y };
        *reinterpret_cast<f32x4*>(olo + r1) = (f32x4){ bL0.x, bL0.y, bL1.x, bL1.y };
        *reinterpret_cast<f32x4*>(ohi + r1) = (f32x4){ bH0.x, bH0.y, bH1.x, bH1.y };
    }
}

extern "C" void kernel_launch(void* const* d_in, const int* in_sizes, int n_in,
                              void* d_out, int out_size, void* d_ws, size_t ws_size,
                              hipStream_t stream) {
    const int*   tok   = (const int*)d_in[0];
    const float* crt   = (const float*)d_in[1];
    const float* cit   = (const float*)d_in[2];
    const float* W     = (const float*)d_in[3];
    const float* scale = (const float*)d_in[4];
    float*       out   = (float*)d_out;

    const size_t feats_bytes = (size_t)TOKENS * NF * sizeof(float);
    if (ws_size >= feats_bytes) {
        float* feats = (float*)d_ws;
        feats_kernel<<<TOKENS / 64, 64, 0, stream>>>(tok, crt, cit, feats);
        proj_kernel<<<TOKENS / TB, 256, 0, stream>>>(feats, W, scale, out);
    } else {
        fused_kernel<<<TOKENS / TB, 256, 0, stream>>>(tok, crt, cit, W, scale, out);
    }
}

// Round 10
// 52.730 us; speedup vs baseline: 1.0924x; 1.0924x over previous
//
#include <hip/hip_runtime.h>

// FractalEmbedding: tokens -> Julia features (16 fp32) -> 16x2048 projection.
// Output 268 MB fp32 => store-bound. Fill ceiling 7 TB/s => ~38-43 us floor.
//
// R10 = R8 (best 53.0) with ONE change: dim->wave remap so each wave owns a
// contiguous 2 KB span of each token row (wave wv -> dims [wv*512,wv*512+512),
// lane quads at wv*512+lane*4 and +256). Stores per wave become one
// sequential 2 KB burst (two adjacent dense 1 KB b128 stores) -> 4 streams
// per block of 2 KB chunks instead of 8 streams of 1 KB. Pure A/B on
// DRAM write-stream shape; instruction count identical to R8.

constexpr int TOKENS = 4 * 8192;   // 32768
constexpr int EMBED  = 2048;
constexpr int NF     = 16;         // 2 * STEPS
constexpr int STEPS  = 8;
constexpr int TB     = 64;         // tokens per block

typedef float f32x2 __attribute__((ext_vector_type(2)));
typedef float f32x4 __attribute__((ext_vector_type(4)));

__global__ __launch_bounds__(256, 2)
void fused_kernel(const int* __restrict__ tok,
                  const float* __restrict__ crt,
                  const float* __restrict__ cit,
                  const float* __restrict__ W,      // [EMBED][NF]
                  const float* __restrict__ scale_p,
                  float* __restrict__ out)          // [TOKENS][EMBED]
{
    const int tid  = threadIdx.x;
    const int wv   = tid >> 6;          // wave 0..3
    const int lane = tid & 63;
    const int dA   = wv * 512 + lane * 4;   // quad A: dense 1 KB across wave
    const int dB   = dA + 256;              // quad B: adjacent dense 1 KB
    const float s  = scale_p[0];

    // Packed weights, scale folded: wp[c][p][k] = {W[d+2p][k], W[d+2p+1][k]}*s
    // c=0 -> dA, c=1 -> dB. 128 VGPR.
    f32x2 wp[2][2][NF];
    #pragma unroll
    for (int c = 0; c < 2; ++c) {
        const int d = (c == 0) ? dA : dB;
        const f32x4* W4 = reinterpret_cast<const f32x4*>(W + (size_t)d * NF);
        #pragma unroll
        for (int p = 0; p < 2; ++p) {
            #pragma unroll
            for (int k = 0; k < 4; ++k) {
                f32x4 a = W4[p * 8 + k];       // row d+2p
                f32x4 b = W4[p * 8 + 4 + k];   // row d+2p+1
                wp[c][p][4 * k + 0] = (f32x2){ a.x * s, b.x * s };
                wp[c][p][4 * k + 1] = (f32x2){ a.y * s, b.y * s };
                wp[c][p][4 * k + 2] = (f32x2){ a.z * s, b.z * s };
                wp[c][p][4 * k + 3] = (f32x2){ a.w * s, b.w * s };
            }
        }
    }

    // Julia features for this block's 64 tokens -> LDS (4 KB).
    __shared__ float feats[TB][NF];
    const int tok0 = blockIdx.x * TB;
    if (tid < TB) {
        const int t = tok[tok0 + tid];
        const float cr = crt[t];
        const float ci = cit[t];
        float zr = 0.0f, zi = 0.0f;
        #pragma unroll
        for (int st = 0; st < STEPS; ++st) {
            const float nzr = zr * zr - zi * zi + cr;
            const float nzi = 2.0f * zr * zi + ci;
            zr = nzr; zi = nzi;
            feats[tid][2 * st]     = zr;
            feats[tid][2 * st + 1] = zi;
        }
    }
    __syncthreads();

    float* __restrict__ oA = out + (size_t)tok0 * EMBED + dA;
    float* __restrict__ oB = out + (size_t)tok0 * EMBED + dB;

    for (int i = 0; i < TB; i += 2) {
        float fa[NF], fb[NF];
        {
            const f32x4* fpa = reinterpret_cast<const f32x4*>(feats[i]);
            const f32x4* fpb = reinterpret_cast<const f32x4*>(feats[i + 1]);
            #pragma unroll
            for (int k = 0; k < 4; ++k) {
                f32x4 va = fpa[k], vb = fpb[k];
                fa[4 * k + 0] = va.x; fa[4 * k + 1] = va.y;
                fa[4 * k + 2] = va.z; fa[4 * k + 3] = va.w;
                fb[4 * k + 0] = vb.x; fb[4 * k + 1] = vb.y;
                fb[4 * k + 2] = vb.z; fb[4 * k + 3] = vb.w;
            }
        }
        f32x2 aA0 = {0.f,0.f}, aA1 = {0.f,0.f}, aB0 = {0.f,0.f}, aB1 = {0.f,0.f};
        f32x2 bA0 = {0.f,0.f}, bA1 = {0.f,0.f}, bB0 = {0.f,0.f}, bB1 = {0.f,0.f};
        #pragma unroll
        for (int k = 0; k < NF; ++k) {
            const f32x2 fA = { fa[k], fa[k] };
            const f32x2 fB = { fb[k], fb[k] };
            aA0 += fA * wp[0][0][k];   // v_pk_fma_f32
            aA1 += fA * wp[0][1][k];
            aB0 += fA * wp[1][0][k];
            aB1 += fA * wp[1][1][k];
            bA0 += fB * wp[0][0][k];
            bA1 += fB * wp[0][1][k];
            bB0 += fB * wp[1][0][k];
            bB1 += fB * wp[1][1][k];
        }
        const size_t r0 = (size_t)i * EMBED;
        const size_t r1 = (size_t)(i + 1) * EMBED;
        *reinterpret_cast<f32x4*>(oA + r0) = (f32x4){ aA0.x, aA0.y, aA1.x, aA1.y };
        *reinterpret_cast<f32x4*>(oB + r0) = (f32x4){ aB0.x, aB0.y, aB1.x, aB1.y };
        *reinterpret_cast<f32x4*>(oA + r1) = (f32x4){ bA0.x, bA0.y, bA1.x, bA1.y };
        *reinterpret_cast<f32x4*>(oB + r1) = (f32x4){ bB0.x, bB0.y, bB1.x, bB1.y };
    }
}

extern "C" void kernel_launch(void* const* d_in, const int* in_sizes, int n_in,
                              void* d_out, int out_size, void* d_ws, size_t ws_size,
                              hipStream_t stream) {
    const int*   tok   = (const int*)d_in[0];
    const float* crt   = (const float*)d_in[1];
    const float* cit   = (const float*)d_in[2];
    const float* W     = (const float*)d_in[3];
    const float* scale = (const float*)d_in[4];
    float*       out   = (float*)d_out;

    fused_kernel<<<TOKENS / TB, 256, 0, stream>>>(tok, crt, cit, W, scale, out);
}

// Round 11
// 50.162 us; speedup vs baseline: 1.1483x; 1.0512x over previous
//
#include <hip/hip_runtime.h>

// FractalEmbedding: tokens -> Julia features (16 fp32) -> 16x2048 projection.
// Output 268 MB fp32 => store-bound. Fill ceiling 7 TB/s => ~38-43 us floor.
//
// R11 = R8/R10 with TB=128: 256 blocks = exactly 1 block/CU, so the
// prologue (W-pack + feats gather + serial Julia chain + barrier) is paid
// ONCE per CU instead of twice. Feats computed by 128 threads (2 waves).
// Everything else unchanged: 256 thr, 8 dims/thread (wave-contiguous 2 KB
// spans from R10), pk_fma with scale folded, 2-token unroll, plain f32x4
// stores, contiguous 1 MB region per block.

constexpr int TOKENS = 4 * 8192;   // 32768
constexpr int EMBED  = 2048;
constexpr int NF     = 16;         // 2 * STEPS
constexpr int STEPS  = 8;
constexpr int TB     = 128;        // tokens per block -> 256 blocks = 1/CU

typedef float f32x2 __attribute__((ext_vector_type(2)));
typedef float f32x4 __attribute__((ext_vector_type(4)));

__global__ __launch_bounds__(256, 2)
void fused_kernel(const int* __restrict__ tok,
                  const float* __restrict__ crt,
                  const float* __restrict__ cit,
                  const float* __restrict__ W,      // [EMBED][NF]
                  const float* __restrict__ scale_p,
                  float* __restrict__ out)          // [TOKENS][EMBED]
{
    const int tid  = threadIdx.x;
    const int wv   = tid >> 6;          // wave 0..3
    const int lane = tid & 63;
    const int dA   = wv * 512 + lane * 4;   // quad A: dense 1 KB across wave
    const int dB   = dA + 256;              // quad B: adjacent dense 1 KB
    const float s  = scale_p[0];

    // Packed weights, scale folded: wp[c][p][k] = {W[d+2p][k], W[d+2p+1][k]}*s
    f32x2 wp[2][2][NF];
    #pragma unroll
    for (int c = 0; c < 2; ++c) {
        const int d = (c == 0) ? dA : dB;
        const f32x4* W4 = reinterpret_cast<const f32x4*>(W + (size_t)d * NF);
        #pragma unroll
        for (int p = 0; p < 2; ++p) {
            #pragma unroll
            for (int k = 0; k < 4; ++k) {
                f32x4 a = W4[p * 8 + k];       // row d+2p
                f32x4 b = W4[p * 8 + 4 + k];   // row d+2p+1
                wp[c][p][4 * k + 0] = (f32x2){ a.x * s, b.x * s };
                wp[c][p][4 * k + 1] = (f32x2){ a.y * s, b.y * s };
                wp[c][p][4 * k + 2] = (f32x2){ a.z * s, b.z * s };
                wp[c][p][4 * k + 3] = (f32x2){ a.w * s, b.w * s };
            }
        }
    }

    // Julia features for this block's 128 tokens -> LDS (8 KB), 2 waves.
    __shared__ float feats[TB][NF];
    const int tok0 = blockIdx.x * TB;
    if (tid < TB) {
        const int t = tok[tok0 + tid];
        const float cr = crt[t];
        const float ci = cit[t];
        float zr = 0.0f, zi = 0.0f;
        #pragma unroll
        for (int st = 0; st < STEPS; ++st) {
            const float nzr = zr * zr - zi * zi + cr;
            const float nzi = 2.0f * zr * zi + ci;
            zr = nzr; zi = nzi;
            feats[tid][2 * st]     = zr;
            feats[tid][2 * st + 1] = zi;
        }
    }
    __syncthreads();

    float* __restrict__ oA = out + (size_t)tok0 * EMBED + dA;
    float* __restrict__ oB = out + (size_t)tok0 * EMBED + dB;

    for (int i = 0; i < TB; i += 2) {
        float fa[NF], fb[NF];
        {
            const f32x4* fpa = reinterpret_cast<const f32x4*>(feats[i]);
            const f32x4* fpb = reinterpret_cast<const f32x4*>(feats[i + 1]);
            #pragma unroll
            for (int k = 0; k < 4; ++k) {
                f32x4 va = fpa[k], vb = fpb[k];
                fa[4 * k + 0] = va.x; fa[4 * k + 1] = va.y;
                fa[4 * k + 2] = va.z; fa[4 * k + 3] = va.w;
                fb[4 * k + 0] = vb.x; fb[4 * k + 1] = vb.y;
                fb[4 * k + 2] = vb.z; fb[4 * k + 3] = vb.w;
            }
        }
        f32x2 aA0 = {0.f,0.f}, aA1 = {0.f,0.f}, aB0 = {0.f,0.f}, aB1 = {0.f,0.f};
        f32x2 bA0 = {0.f,0.f}, bA1 = {0.f,0.f}, bB0 = {0.f,0.f}, bB1 = {0.f,0.f};
        #pragma unroll
        for (int k = 0; k < NF; ++k) {
            const f32x2 fA = { fa[k], fa[k] };
            const f32x2 fB = { fb[k], fb[k] };
            aA0 += fA * wp[0][0][k];   // v_pk_fma_f32
            aA1 += fA * wp[0][1][k];
            aB0 += fA * wp[1][0][k];
            aB1 += fA * wp[1][1][k];
            bA0 += fB * wp[0][0][k];
            bA1 += fB * wp[0][1][k];
            bB0 += fB * wp[1][0][k];
            bB1 += fB * wp[1][1][k];
        }
        const size_t r0 = (size_t)i * EMBED;
        const size_t r1 = (size_t)(i + 1) * EMBED;
        *reinterpret_cast<f32x4*>(oA + r0) = (f32x4){ aA0.x, aA0.y, aA1.x, aA1.y };
        *reinterpret_cast<f32x4*>(oB + r0) = (f32x4){ aB0.x, aB0.y, aB1.x, aB1.y };
        *reinterpret_cast<f32x4*>(oA + r1) = (f32x4){ bA0.x, bA0.y, bA1.x, bA1.y };
        *reinterpret_cast<f32x4*>(oB + r1) = (f32x4){ bB0.x, bB0.y, bB1.x, bB1.y };
    }
}

extern "C" void kernel_launch(void* const* d_in, const int* in_sizes, int n_in,
                              void* d_out, int out_size, void* d_ws, size_t ws_size,
                              hipStream_t stream) {
    const int*   tok   = (const int*)d_in[0];
    const float* crt   = (const float*)d_in[1];
    const float* cit   = (const float*)d_in[2];
    const float* W     = (const float*)d_in[3];
    const float* scale = (const float*)d_in[4];
    float*       out   = (float*)d_out;

    fused_kernel<<<TOKENS / TB, 256, 0, stream>>>(tok, crt, cit, W, scale, out);
}